// Round 1
// baseline (127.848 us; speedup 1.0000x reference)
//
#include <hip/hip_runtime.h>
#include <hip/hip_cooperative_groups.h>

namespace cg = cooperative_groups;

#define N_FFT 32000
#define NBINS 16001
#define NDL 8
#define NAP 4
#define EARLY_LEN 200
#define T_LEN 32000
#define NB 4

#define ASTRIDE 65600      // padded audio_h stride per batch (halves)
#define APAD 16000         // left zero pad in audio_h

// conv geometry (32x32x16 MFMA implicit GEMM, taps truncated at 16384)
#define KSPLIT 16
#define KRANGE 1024        // taps per kz
#define KTOT   16384
#define OB 4096            // outputs per block per batch
#define WSPAN 5088         // logical x window halves per batch
#define XPHYS 5760         // physical (padded) x window halves
#define HS_ROW_L 1048      // hs LDS row halves (524 words = 12 mod 32)

struct c32 { float re, im; };

__device__ __forceinline__ c32 cmul(c32 a, c32 b) {
    return { a.re*b.re - a.im*b.im, a.re*b.im + a.im*b.re };
}
__device__ __forceinline__ c32 cdiv(c32 a, c32 b) {
    float inv = 1.0f / (b.re*b.re + b.im*b.im);
    return { (a.re*b.re + a.im*b.im)*inv, (a.im*b.re - a.re*b.im)*inv };
}

typedef _Float16 f16x8 __attribute__((ext_vector_type(8)));
typedef float    f32x16 __attribute__((ext_vector_type(16)));

__device__ __forceinline__ float h2f(unsigned short u) {
    return (float)__builtin_bit_cast(_Float16, u);
}
__device__ __forceinline__ unsigned short f2h(float f) {
    return __builtin_bit_cast(unsigned short, (_Float16)f);
}

// ---------------------------------------------------------------------------
// ONE cooperative kernel, 4 phases separated by grid.sync():
//   P1 (blocks 0..124): transfer bins + k2-DFT -> G
//      (blocks 125..255): audio f32 -> padded f16 audio_h
//   P2 (all blocks): outer DFT -> h_g[0..16384) f16 (+early), 8-lane split-k1
//   P3 (all blocks): MFMA conv -> pconv f16 partials
//   P4 (all blocks): sum split-k partials -> out
// ---------------------------------------------------------------------------
__global__ __launch_bounds__(512, 2) void fused_kernel(
    const float* __restrict__ audio, const float* __restrict__ early,
    const float* __restrict__ ing, const float* __restrict__ outg,
    const float* __restrict__ t0p, const float* __restrict__ alphap,
    const float* __restrict__ delays, const float* __restrict__ dap,
    const float* __restrict__ gap,
    float2* __restrict__ G, unsigned short* __restrict__ audio_h,
    unsigned short* __restrict__ h_g, unsigned short* __restrict__ pconv,
    float* __restrict__ out)
{
    __shared__ __attribute__((aligned(16))) char Sraw[2*XPHYS*2 + 32*HS_ROW_L*2 + 1056*2];
    cg::grid_group grid = cg::this_grid();

    int tid = threadIdx.x;
    int bid = blockIdx.x;
    const float TWf = 1.9634954084936207e-04f;   // 2*pi/32000

    // ======================= Phase 1 =======================
    if (bid < 125) {
        float2* sxA = (float2*)Sraw;             // 129
        float2* tab = (float2*)(Sraw + 1040);    // 256
        float2* pa  = (float2*)(Sraw + 3088);    // 512
        int k1 = bid;

        if (tid < 256) {
            float c, s;
            sincosf(2.4544246578366045e-02f * (float)tid, &s, &c);  // 2*pi/256
            tab[tid] = make_float2(c, s);
        }

        const double TWd = 1.9634954084936207740e-04;
        float t0v = t0p[0], alpha = alphap[0];

        for (int base = 0; base < 1032; base += 512) {
            int task = base + tid;
            if (task >= 1032) break;
            int k2 = task >> 3, d = task & 7;
            int f = k1 + 125 * k2;
            if (f > 16000) { if (d == 0) sxA[k2] = make_float2(0.f, 0.f); continue; }

            float wk = TWf * (float)f;
            float cwk, swk;
            sincosf(wk, &swk, &cwk);

            float dval = delays[d];
            float fid = floorf(dval);
            float d_eta = dval - fid;
            float eta = (1.0f - d_eta) / (1.0f + d_eta);
            long long mm = ((long long)f * (long long)fid) % N_FFT;
            float a0 = TWf * (float)mm;
            float c0, s0; sincosf(a0, &s0, &c0);
            c32 z_d = { c0, -s0 };
            c32 num = { eta + cwk, -swk };
            c32 den = { 1.0f + eta*cwk, -eta*swk };
            c32 dvec = cmul(z_d, cdiv(num, den));

            float dsum = dval;
            #pragma unroll
            for (int a = 0; a < NAP; a++) dsum += dap[d*NAP + a];
            float delay_sec = dsum * (1.0f/16000.0f);
            float kf  = expf(-3.0f*delay_sec/t0v * 2.3025850929940457f);
            float kpi = expf(-3.0f*delay_sec/(alpha*t0v) * 2.3025850929940457f);
            float g = 2.0f*kf*kpi/(kf+kpi);
            float p = (kf - kpi)/(kf + kpi);
            c32 fden = { 1.0f + 1e-8f - p*cwk, p*swk };
            c32 filt = cdiv({g, 0.f}, fden);

            c32 ap = {1.f, 0.f};
            #pragma unroll
            for (int a = 0; a < NAP; a++) {
                float dl = dap[d*NAP + a];
                double ph = fmod((double)f * (double)dl, (double)N_FFT);
                float aa = (float)(ph * TWd);
                float ca, sa; sincosf(aa, &sa, &ca);
                float ga = gap[d*NAP + a];
                c32 nume = { 1.0f + ga*ca, ga*sa };
                c32 dene = { ga + ca, sa };
                ap = cmul(ap, cdiv(nume, dene));
            }
            c32 cd = cmul(ap, dvec);
            c32 rc = cmul(filt, cd);
            c32 Dd = { 1.0f + rc.re, rc.im };
            c32 invD = cdiv({1.f, 0.f}, Dd);
            float bg = ing[d];
            c32 t1 = cmul({cd.re*bg, cd.im*bg}, invD);
            c32 t2 = cmul(rc, invD);
            float s1r = t1.re, s1i = t1.im, s2r = t2.re, s2i = t2.im;
            #pragma unroll
            for (int msk = 1; msk < 8; msk <<= 1) {
                s1r += __shfl_xor(s1r, msk);
                s1i += __shfl_xor(s1i, msk);
                s2r += __shfl_xor(s2r, msk);
                s2i += __shfl_xor(s2i, msk);
            }
            c32 denl = { 1.0f - 0.5f*s2r, -0.5f*s2i };
            c32 lam = cdiv({0.5f*s1r, 0.5f*s1i}, denl);
            c32 lr = cmul(lam, filt);
            c32 xv = cmul(invD, {bg + lr.re, lr.im});
            c32 term = cmul(dvec, xv);
            float og = outg[d];
            float trr = term.re * og, tri = term.im * og;
            #pragma unroll
            for (int msk = 1; msk < 8; msk <<= 1) {
                trr += __shfl_xor(trr, msk);
                tri += __shfl_xor(tri, msk);
            }
            if (d == 0) {
                float w = (f == 0 || f == 16000) ? 0.5f : 1.0f;
                sxA[k2] = make_float2(trr * w, tri * w);
            }
        }
        __syncthreads();

        // split-k2 DFT (2 threads per r)
        {
            int r = tid & 255, half = tid >> 8;
            int k2s = half ? 65 : 0, k2e = half ? 129 : 65;
            float ar = 0.f, ai = 0.f;
            int p = (k2s * r) & 255;
            for (int k2 = k2s; k2 < k2e; k2++) {
                float2 X = sxA[k2];
                float2 E = tab[p];
                ar = fmaf(X.x, E.x, fmaf(-X.y, E.y, ar));
                ai = fmaf(X.x, E.y, fmaf( X.y, E.x, ai));
                p = (p + r) & 255;
            }
            pa[tid] = make_float2(ar, ai);
        }
        __syncthreads();
        if (tid < 256) {
            float2 a = pa[tid], b = pa[tid + 256];
            G[k1 * 256 + tid] = make_float2(a.x + b.x, a.y + b.y);
        }
    } else {
        // -------- audio conversion --------
        int i4 = (bid - 125) * 512 + tid;
        if (i4 < NB * (ASTRIDE/8)) {
            int b = i4 / (ASTRIDE/8);
            int q = i4 - b * (ASTRIDE/8);
            int u0 = q * 8 - APAD;
            unsigned r[4];
            if (u0 >= 0 && u0 + 8 <= T_LEN) {
                const float4* apx = (const float4*)(audio + b*T_LEN + u0);
                float4 v0 = apx[0], v1 = apx[1];
                r[0] = f2h(v0.x) | ((unsigned)f2h(v0.y) << 16);
                r[1] = f2h(v0.z) | ((unsigned)f2h(v0.w) << 16);
                r[2] = f2h(v1.x) | ((unsigned)f2h(v1.y) << 16);
                r[3] = f2h(v1.z) | ((unsigned)f2h(v1.w) << 16);
            } else {
                unsigned short hh[8];
                #pragma unroll
                for (int e = 0; e < 8; e++) {
                    int u = u0 + e;
                    float v = (u >= 0 && u < T_LEN) ? audio[b*T_LEN + u] : 0.0f;
                    hh[e] = f2h(v);
                }
                r[0] = hh[0] | ((unsigned)hh[1] << 16);
                r[1] = hh[2] | ((unsigned)hh[3] << 16);
                r[2] = hh[4] | ((unsigned)hh[5] << 16);
                r[3] = hh[6] | ((unsigned)hh[7] << 16);
            }
            ((uint4*)audio_h)[i4] = make_uint4(r[0], r[1], r[2], r[3]);
        }
    }

    grid.sync();

    // ======================= Phase 2: h_g =======================
    // ir[n] = (2/N) Re sum_{k1<125} G[k1][n&255] e^{2pi i k1 n/N}
    // 8 lanes per n, each covering 16 (last: 13) k1 values.
    {
        int n   = bid * 64 + (tid >> 3);           // 256*64 = 16384
        int sub = tid & 7;
        int k10 = sub * 16;
        int nk1 = (sub == 7) ? 13 : 16;

        int m0 = (n * k10) % N_FFT;                 // exact integer phase
        float er, ei; sincosf(TWf * (float)m0, &ei, &er);
        float wc, wss; sincosf(TWf * (float)n, &wss, &wc);

        float ar = 0.f;
        const float2* gp = G + (n & 255) + (size_t)k10 * 256;
        #pragma unroll 4
        for (int k = 0; k < nk1; k++) {
            float2 g = gp[(size_t)k * 256];
            ar = fmaf(g.x, er, fmaf(-g.y, ei, ar));
            float nr = fmaf(er, wc, -(ei*wss));
            float ni = fmaf(er, wss,  (ei*wc));
            er = nr; ei = ni;
        }
        ar += __shfl_xor(ar, 1);
        ar += __shfl_xor(ar, 2);
        ar += __shfl_xor(ar, 4);
        if (sub == 0) {
            float v = ar * (2.0f / (float)N_FFT);
            if (n < EARLY_LEN) v += early[n];
            h_g[n] = f2h(v);
        }
    }

    grid.sync();

    // ======================= Phase 3: conv =======================
    {
        _Float16* xs = (_Float16*)Sraw;                        // [2][XPHYS]
        _Float16* hs = (_Float16*)(Sraw + 2*XPHYS*2);          // [32][HS_ROW_L]
        _Float16* hw = (_Float16*)(Sraw + 2*XPHYS*2 + 32*HS_ROW_L*2); // [1056]
        float*    red = (float*)Sraw;                          // epilogue reuse

        int lane = tid & 63;
        int w = tid >> 6;
        int bb = w & 1;
        int tq = (w >> 1) & 1;
        int kw = w >> 2;
        int bx = bid & 7, bp = (bid >> 3) & 1, kz = bid >> 4;
        int t0 = bx * OB;
        int b0g = bp * 2;
        int K0 = kz * KRANGE;
        int wbase = t0 + K0;

        // ---- stage h window [K0-32, K0+1024) from h_g ----
        {
            unsigned* hw32 = (unsigned*)hw;
            const unsigned* hg32 = (const unsigned*)h_g;
            int sbase = (K0 - 32) >> 1;                 // exact (even)
            for (int j2 = tid; j2 < 528; j2 += 512)
                hw32[j2] = (sbase + j2 >= 0) ? hg32[sbase + j2] : 0u;
        }
        // ---- stage x windows (2 batches) from pre-converted audio_h ----
        const uint4* xg = (const uint4*)audio_h;
        for (int q = tid; q < 2 * (WSPAN/8); q += 512) {
            int bbs = (q >= WSPAN/8) ? 1 : 0;
            int qq = q - (WSPAN/8) * bbs;
            uint4 v = xg[(size_t)(b0g + bbs) * (ASTRIDE/8) + (wbase >> 3) + qq];
            ((uint4*)xs)[bbs * (XPHYS/8) + qq + (qq >> 3)] = v;
        }
        __syncthreads();

        // ---- build 32-row shifted band: hs[i][m] = hw[m - i + 31] ----
        // i per lane (tid&31), q wave-uniform octet -> reads are ~conflict-free
        {
            const unsigned short* hwu = (const unsigned short*)hw;
            int i  = tid & 31;          // row (shift), constant per thread
            int q0 = tid >> 5;          // 0..15
            #pragma unroll
            for (int e = 0; e < 8; e++) {
                int q = q0 + 16 * e;    // 0..127
                int src = 8 * q - i + 31;
                unsigned o[4];
                #pragma unroll
                for (int j = 0; j < 4; j++)
                    o[j] = (unsigned)hwu[src + 2*j] | ((unsigned)hwu[src + 2*j + 1] << 16);
                *(uint4*)(hs + i * HS_ROW_L + 8 * q) = make_uint4(o[0], o[1], o[2], o[3]);
            }
        }
        __syncthreads();

        int l31 = lane & 31, g = lane >> 5;
        int aBase = l31 * HS_ROW_L + 8 * g;
        int pB0 = 1024 * (2*tq + 0) + 32 * l31 + 8 * g;
        int pB1 = 1024 * (2*tq + 1) + 32 * l31 + 8 * g;
        const _Float16* xb = xs + (bb ? XPHYS : 0);

        f32x16 acc0 = {0,0,0,0,0,0,0,0,0,0,0,0,0,0,0,0};
        f32x16 acc1 = {0,0,0,0,0,0,0,0,0,0,0,0,0,0,0,0};
        #pragma unroll 4
        for (int ksl = 0; ksl < 32; ksl++) {
            int ksg = kw * 32 + ksl;
            f16x8 af = *(const f16x8*)(hs + aBase + 16 * ksg);
            int p0 = pB0 + 16 * ksg;
            int p1 = pB1 + 16 * ksg;
            f16x8 bf0 = *(const f16x8*)(xb + p0 + 8 * (p0 >> 6));
            f16x8 bf1 = *(const f16x8*)(xb + p1 + 8 * (p1 >> 6));
            acc0 = __builtin_amdgcn_mfma_f32_32x32x16_f16(af, bf0, acc0, 0, 0, 0);
            acc1 = __builtin_amdgcn_mfma_f32_32x32x16_f16(af, bf1, acc1, 0, 0, 0);
        }
        __syncthreads();
        int slot0 = ((bb * 2 + tq) * 2 + 0) * 1024;
        int slot1 = ((bb * 2 + tq) * 2 + 1) * 1024;
        if (kw == 1) {
            #pragma unroll
            for (int r = 0; r < 16; r++) {
                red[slot0 + r * 64 + lane] = acc0[r];
                red[slot1 + r * 64 + lane] = acc1[r];
            }
        }
        __syncthreads();
        if (kw == 0) {
            unsigned short* po = pconv + (size_t)(kz * NB + b0g + bb) * T_LEN;
            #pragma unroll
            for (int s = 0; s < 2; s++) {
                int T = 2 * tq + s;
                int slot = s ? slot1 : slot0;
                #pragma unroll
                for (int r = 0; r < 16; r += 2) {
                    float v0 = (s ? acc1[r]   : acc0[r])   + red[slot + r * 64 + lane];
                    float v1 = (s ? acc1[r+1] : acc0[r+1]) + red[slot + (r+1) * 64 + lane];
                    int i = (r & 3) + 8 * (r >> 2) + 4 * g;
                    int t = t0 + 1024 * T + i + 32 * l31;
                    if (t < T_LEN) {
                        unsigned u = f2h(v0) | ((unsigned)f2h(v1) << 16);
                        *(unsigned*)(po + t) = u;
                    }
                }
            }
        }
    }

    grid.sync();

    // ======================= Phase 4: finish =======================
    {
        int i = bid * 512 + tid;
        if (i < NB * T_LEN) {
            float s = 0.f;
            #pragma unroll
            for (int kz = 0; kz < KSPLIT; kz++)
                s += h2f(pconv[(size_t)kz * NB * T_LEN + i]);
            out[i] = s;
        }
    }
}

extern "C" void kernel_launch(void* const* d_in, const int* in_sizes, int n_in,
                              void* d_out, int out_size, void* d_ws, size_t ws_size,
                              hipStream_t stream) {
    const float* audio  = (const float*)d_in[0];
    const float* early  = (const float*)d_in[1];
    const float* ing    = (const float*)d_in[2];
    const float* outg   = (const float*)d_in[3];
    const float* t0p    = (const float*)d_in[4];
    const float* alphap = (const float*)d_in[5];
    const float* delays = (const float*)d_in[6];
    const float* dap    = (const float*)d_in[7];
    const float* gap    = (const float*)d_in[8];

    char* ws = (char*)d_ws;
    float2*         G       = (float2*)(ws);                    // 256,000 B
    unsigned short* h_g     = (unsigned short*)(ws + 262144);   // 32,768 B
    unsigned short* audio_h = (unsigned short*)(ws + 294912);   // 524,800 B
    unsigned short* pconv   = (unsigned short*)(ws + 819712);   // 4,096,000 B
    float*          outp    = (float*)d_out;

    void* args[] = { (void*)&audio, (void*)&early, (void*)&ing, (void*)&outg,
                     (void*)&t0p, (void*)&alphap, (void*)&delays, (void*)&dap,
                     (void*)&gap, (void*)&G, (void*)&audio_h, (void*)&h_g,
                     (void*)&pconv, (void*)&outp };
    hipLaunchCooperativeKernel(fused_kernel, dim3(256), dim3(512), args, 0, stream);
}

// Round 3
// 93.319 us; speedup vs baseline: 1.3700x; 1.3700x over previous
//
#include <hip/hip_runtime.h>

#define N_FFT 32000
#define NBINS 16001
#define NDL 8
#define NAP 4
#define EARLY_LEN 200
#define T_LEN 32000
#define NB 4

#define ASTRIDE 65600      // padded audio_h stride per batch (halves)
#define APAD 16000         // left zero pad in audio_h

// conv geometry (32x32x16 MFMA implicit GEMM, taps truncated at 16384)
#define KSPLIT 16
#define KRANGE 1024        // taps per kz
#define KTOT   16384
#define OB 4096            // outputs per block per batch
#define WSPAN 5088         // logical x window halves per batch
#define XPHYS 5760         // physical (padded) x window halves
#define HS_ROW_L 1048      // hs LDS row halves (524 words = 12 mod 32)

struct c32 { float re, im; };

__device__ __forceinline__ c32 cmul(c32 a, c32 b) {
    return { a.re*b.re - a.im*b.im, a.re*b.im + a.im*b.re };
}
__device__ __forceinline__ c32 cdiv(c32 a, c32 b) {
    float inv = 1.0f / (b.re*b.re + b.im*b.im);
    return { (a.re*b.re + a.im*b.im)*inv, (a.im*b.re - a.re*b.im)*inv };
}

typedef _Float16 f16x8 __attribute__((ext_vector_type(8)));
typedef float    f32x16 __attribute__((ext_vector_type(16)));

__device__ __forceinline__ float h2f(unsigned short u) {
    return (float)__builtin_bit_cast(_Float16, u);
}
__device__ __forceinline__ unsigned short f2h(float f) {
    return __builtin_bit_cast(unsigned short, (_Float16)f);
}

// ------- Kernel 1: blocks <125: transfer bins + k2-DFT -> G ----------------
//         blocks >=125: audio f32 -> padded f16 audio_h
__global__ __launch_bounds__(512) void stageAT_kernel(
    const float* __restrict__ ing, const float* __restrict__ outg,
    const float* __restrict__ t0p, const float* __restrict__ alphap,
    const float* __restrict__ delays, const float* __restrict__ dap,
    const float* __restrict__ gap, float2* __restrict__ G,
    const float* __restrict__ audio, unsigned short* __restrict__ audio_h)
{
    __shared__ float2 sxA[129];
    __shared__ float2 tab[256];
    __shared__ float2 pa[512];
    int tid = threadIdx.x;
    int k1 = blockIdx.x;

    if (k1 >= 125) {            // -------- audio conversion part --------
        int i4 = (k1 - 125) * 512 + tid;
        if (i4 >= NB * (ASTRIDE/8)) return;
        int b = i4 / (ASTRIDE/8);
        int q = i4 - b * (ASTRIDE/8);
        int u0 = q * 8 - APAD;
        unsigned r[4];
        if (u0 >= 0 && u0 + 8 <= T_LEN) {
            const float4* ap = (const float4*)(audio + b*T_LEN + u0);
            float4 v0 = ap[0], v1 = ap[1];
            r[0] = f2h(v0.x) | ((unsigned)f2h(v0.y) << 16);
            r[1] = f2h(v0.z) | ((unsigned)f2h(v0.w) << 16);
            r[2] = f2h(v1.x) | ((unsigned)f2h(v1.y) << 16);
            r[3] = f2h(v1.z) | ((unsigned)f2h(v1.w) << 16);
        } else {
            unsigned short hh[8];
            #pragma unroll
            for (int e = 0; e < 8; e++) {
                int u = u0 + e;
                float v = (u >= 0 && u < T_LEN) ? audio[b*T_LEN + u] : 0.0f;
                hh[e] = f2h(v);
            }
            r[0] = hh[0] | ((unsigned)hh[1] << 16);
            r[1] = hh[2] | ((unsigned)hh[3] << 16);
            r[2] = hh[4] | ((unsigned)hh[5] << 16);
            r[3] = hh[6] | ((unsigned)hh[7] << 16);
        }
        ((uint4*)audio_h)[i4] = make_uint4(r[0], r[1], r[2], r[3]);
        return;
    }

    if (tid < 256) {
        float c, s;
        sincosf(2.4544246578366045e-02f * (float)tid, &s, &c);  // 2*pi/256
        tab[tid] = make_float2(c, s);
    }

    const float  TWf = 1.9634954084936207e-04f;   // 2*pi/32000
    const double TWd = 1.9634954084936207740e-04;
    float t0v = t0p[0], alpha = alphap[0];

    for (int base = 0; base < 1032; base += 512) {
        int task = base + tid;
        if (task >= 1032) break;
        int k2 = task >> 3, d = task & 7;
        int f = k1 + 125 * k2;
        if (f > 16000) { if (d == 0) sxA[k2] = make_float2(0.f, 0.f); continue; }

        float wk = TWf * (float)f;
        float cwk, swk;
        sincosf(wk, &swk, &cwk);

        float dval = delays[d];
        float fid = floorf(dval);
        float d_eta = dval - fid;
        float eta = (1.0f - d_eta) / (1.0f + d_eta);
        long long mm = ((long long)f * (long long)fid) % N_FFT;
        float a0 = TWf * (float)mm;
        float c0, s0; sincosf(a0, &s0, &c0);
        c32 z_d = { c0, -s0 };
        c32 num = { eta + cwk, -swk };
        c32 den = { 1.0f + eta*cwk, -eta*swk };
        c32 dvec = cmul(z_d, cdiv(num, den));

        float dsum = dval;
        #pragma unroll
        for (int a = 0; a < NAP; a++) dsum += dap[d*NAP + a];
        float delay_sec = dsum * (1.0f/16000.0f);
        float kf  = expf(-3.0f*delay_sec/t0v * 2.3025850929940457f);
        float kpi = expf(-3.0f*delay_sec/(alpha*t0v) * 2.3025850929940457f);
        float g = 2.0f*kf*kpi/(kf+kpi);
        float p = (kf - kpi)/(kf + kpi);
        c32 fden = { 1.0f + 1e-8f - p*cwk, p*swk };
        c32 filt = cdiv({g, 0.f}, fden);

        c32 ap = {1.f, 0.f};
        #pragma unroll
        for (int a = 0; a < NAP; a++) {
            float dl = dap[d*NAP + a];
            double ph = fmod((double)f * (double)dl, (double)N_FFT);
            float aa = (float)(ph * TWd);
            float ca, sa; sincosf(aa, &sa, &ca);
            float ga = gap[d*NAP + a];
            c32 nume = { 1.0f + ga*ca, ga*sa };
            c32 dene = { ga + ca, sa };
            ap = cmul(ap, cdiv(nume, dene));
        }
        c32 cd = cmul(ap, dvec);
        c32 rc = cmul(filt, cd);
        c32 Dd = { 1.0f + rc.re, rc.im };
        c32 invD = cdiv({1.f, 0.f}, Dd);
        float bg = ing[d];
        c32 t1 = cmul({cd.re*bg, cd.im*bg}, invD);
        c32 t2 = cmul(rc, invD);
        float s1r = t1.re, s1i = t1.im, s2r = t2.re, s2i = t2.im;
        #pragma unroll
        for (int msk = 1; msk < 8; msk <<= 1) {
            s1r += __shfl_xor(s1r, msk);
            s1i += __shfl_xor(s1i, msk);
            s2r += __shfl_xor(s2r, msk);
            s2i += __shfl_xor(s2i, msk);
        }
        c32 denl = { 1.0f - 0.5f*s2r, -0.5f*s2i };
        c32 lam = cdiv({0.5f*s1r, 0.5f*s1i}, denl);
        c32 lr = cmul(lam, filt);
        c32 xv = cmul(invD, {bg + lr.re, lr.im});
        c32 term = cmul(dvec, xv);
        float og = outg[d];
        float trr = term.re * og, tri = term.im * og;
        #pragma unroll
        for (int msk = 1; msk < 8; msk <<= 1) {
            trr += __shfl_xor(trr, msk);
            tri += __shfl_xor(tri, msk);
        }
        if (d == 0) {
            float w = (f == 0 || f == 16000) ? 0.5f : 1.0f;
            sxA[k2] = make_float2(trr * w, tri * w);
        }
    }
    __syncthreads();

    // ---- phase A: split-k2 DFT (2 threads per r) ----
    {
        int r = tid & 255, half = tid >> 8;
        int k2s = half ? 65 : 0, k2e = half ? 129 : 65;
        float ar = 0.f, ai = 0.f;
        int p = (k2s * r) & 255;
        for (int k2 = k2s; k2 < k2e; k2++) {
            float2 X = sxA[k2];
            float2 E = tab[p];
            ar = fmaf(X.x, E.x, fmaf(-X.y, E.y, ar));
            ai = fmaf(X.x, E.y, fmaf( X.y, E.x, ai));
            p = (p + r) & 255;
        }
        pa[tid] = make_float2(ar, ai);
    }
    __syncthreads();
    if (tid < 256) {
        float2 a = pa[tid], b = pa[tid + 256];
        G[k1 * 256 + tid] = make_float2(a.x + b.x, a.y + b.y);
    }
}

// ------- Kernel 2: MFMA conv; h-window DFT inlined (branchless n-guard) ----
__global__ __launch_bounds__(512) void conv_mfma_kernel(
    const unsigned short* __restrict__ audio_h,
    const float2* __restrict__ G,
    const float* __restrict__ early,
    unsigned short* __restrict__ pconv)
{
    __shared__ __attribute__((aligned(16))) char Sraw[2*XPHYS*2 + 32*HS_ROW_L*2 + 1056*2];
    _Float16* xs = (_Float16*)Sraw;                        // [2][XPHYS]
    _Float16* hs = (_Float16*)(Sraw + 2*XPHYS*2);          // [32][HS_ROW_L]
    _Float16* hw = (_Float16*)(Sraw + 2*XPHYS*2 + 32*HS_ROW_L*2); // [1056]
    float*    red = (float*)Sraw;                          // epilogue reuse

    int tid = threadIdx.x;
    int lane = tid & 63;
    int w = tid >> 6;
    int bb = w & 1;
    int tq = (w >> 1) & 1;
    int kw = w >> 2;
    int bx = blockIdx.x, bp = blockIdx.y, kz = blockIdx.z;
    int t0 = bx * OB;
    int b0g = bp * 2;
    int K0 = kz * KRANGE;
    int wbase = t0 + K0;
    const float TWf = 1.9634954084936207e-04f;   // 2*pi/32000

    // ---- stage x windows (2 batches) from pre-converted audio_h ----
    const uint4* xg = (const uint4*)audio_h;
    for (int q = tid; q < 2 * (WSPAN/8); q += 512) {
        int bbs = (q >= WSPAN/8) ? 1 : 0;
        int qq = q - (WSPAN/8) * bbs;
        uint4 v = xg[(size_t)(b0g + bbs) * (ASTRIDE/8) + (wbase >> 3) + qq];
        ((uint4*)xs)[bbs * (XPHYS/8) + qq + (qq >> 3)] = v;
    }

    // ---- h window [K0-32, K0+1024): inline DFT from G, 8 lanes per sample --
    // ir[n] = (2/N) Re sum_{k1<125} G[k1][n&255] e^{2pi i k1 n/N}
    // Branchless n<0 guard: compute with nn=max(n,0), select 0 at the store.
    {
        int n0 = K0 - 32;
        for (int task = tid; task < 8448; task += 512) {   // 1056 samples x 8 lanes
            int j = task >> 3, sub = task & 7;
            int n = n0 + j;
            int nn = n < 0 ? 0 : n;
            int k10 = sub * 16;
            int nk1 = (sub == 7) ? 13 : 16;
            int m0 = (nn * k10) % N_FFT;                   // exact integer phase
            float er, ei; sincosf(TWf * (float)m0, &ei, &er);
            float wc, wss; sincosf(TWf * (float)nn, &wss, &wc);
            float ar = 0.f;
            const float2* gp = G + (nn & 255) + k10 * 256;
            #pragma unroll 4
            for (int k = 0; k < nk1; k++) {
                float2 g2 = gp[k * 256];
                ar = fmaf(g2.x, er, fmaf(-g2.y, ei, ar));
                float nr = fmaf(er, wc, -(ei*wss));
                float ni = fmaf(er, wss,  (ei*wc));
                er = nr; ei = ni;
            }
            ar += __shfl_xor(ar, 1);
            ar += __shfl_xor(ar, 2);
            ar += __shfl_xor(ar, 4);
            if (sub == 0) {
                float v = ar * (2.0f / (float)N_FFT);
                if (kz == 0 && (unsigned)n < EARLY_LEN) v += early[n];
                hw[j] = (_Float16)((n < 0) ? 0.0f : v);
            }
        }
    }
    __syncthreads();

    // ---- build 32-row shifted band: hs[i][m] = hw[m - i + 31] ----
    // i per lane (tid&31), wave-uniform octet (R1-validated scalar gather)
    {
        const unsigned short* hwu = (const unsigned short*)hw;
        int i  = tid & 31;          // row (shift), constant per thread
        int q0 = tid >> 5;          // 0..15
        #pragma unroll
        for (int e = 0; e < 8; e++) {
            int q = q0 + 16 * e;    // 0..127
            int src = 8 * q - i + 31;
            unsigned o[4];
            #pragma unroll
            for (int j = 0; j < 4; j++)
                o[j] = (unsigned)hwu[src + 2*j] | ((unsigned)hwu[src + 2*j + 1] << 16);
            *(uint4*)(hs + i * HS_ROW_L + 8 * q) = make_uint4(o[0], o[1], o[2], o[3]);
        }
    }
    __syncthreads();

    int l31 = lane & 31, g = lane >> 5;
    int aBase = l31 * HS_ROW_L + 8 * g;
    int pB0 = 1024 * (2*tq + 0) + 32 * l31 + 8 * g;
    int pB1 = 1024 * (2*tq + 1) + 32 * l31 + 8 * g;
    const _Float16* xb = xs + (bb ? XPHYS : 0);

    f32x16 acc0 = {0,0,0,0,0,0,0,0,0,0,0,0,0,0,0,0};
    f32x16 acc1 = {0,0,0,0,0,0,0,0,0,0,0,0,0,0,0,0};
    #pragma unroll 4
    for (int ksl = 0; ksl < 32; ksl++) {
        int ksg = kw * 32 + ksl;
        f16x8 af = *(const f16x8*)(hs + aBase + 16 * ksg);
        int p0 = pB0 + 16 * ksg;
        int p1 = pB1 + 16 * ksg;
        f16x8 bf0 = *(const f16x8*)(xb + p0 + 8 * (p0 >> 6));
        f16x8 bf1 = *(const f16x8*)(xb + p1 + 8 * (p1 >> 6));
        acc0 = __builtin_amdgcn_mfma_f32_32x32x16_f16(af, bf0, acc0, 0, 0, 0);
        acc1 = __builtin_amdgcn_mfma_f32_32x32x16_f16(af, bf1, acc1, 0, 0, 0);
    }
    __syncthreads();
    int slot0 = ((bb * 2 + tq) * 2 + 0) * 1024;
    int slot1 = ((bb * 2 + tq) * 2 + 1) * 1024;
    if (kw == 1) {
        #pragma unroll
        for (int r = 0; r < 16; r++) {
            red[slot0 + r * 64 + lane] = acc0[r];
            red[slot1 + r * 64 + lane] = acc1[r];
        }
    }
    __syncthreads();
    if (kw == 0) {
        unsigned short* po = pconv + (size_t)(kz * NB + b0g + bb) * T_LEN;
        #pragma unroll
        for (int s = 0; s < 2; s++) {
            int T = 2 * tq + s;
            int slot = s ? slot1 : slot0;
            #pragma unroll
            for (int r = 0; r < 16; r += 2) {
                float v0 = (s ? acc1[r]   : acc0[r])   + red[slot + r * 64 + lane];
                float v1 = (s ? acc1[r+1] : acc0[r+1]) + red[slot + (r+1) * 64 + lane];
                int i = (r & 3) + 8 * (r >> 2) + 4 * g;
                int t = t0 + 1024 * T + i + 32 * l31;
                if (t < T_LEN) {
                    unsigned u = f2h(v0) | ((unsigned)f2h(v1) << 16);
                    *(unsigned*)(po + t) = u;
                }
            }
        }
    }
}

// ------- Kernel 3: sum the split-k partials (sole d_out writer) ------------
__global__ void finish_kernel(const unsigned short* __restrict__ pconv,
                              float* __restrict__ out)
{
    int i = blockIdx.x * 256 + threadIdx.x;
    if (i >= NB * T_LEN) return;
    float s = 0.f;
    #pragma unroll
    for (int kz = 0; kz < KSPLIT; kz++)
        s += h2f(pconv[(size_t)kz * NB * T_LEN + i]);
    out[i] = s;
}

extern "C" void kernel_launch(void* const* d_in, const int* in_sizes, int n_in,
                              void* d_out, int out_size, void* d_ws, size_t ws_size,
                              hipStream_t stream) {
    const float* audio  = (const float*)d_in[0];
    const float* early  = (const float*)d_in[1];
    const float* ing    = (const float*)d_in[2];
    const float* outg   = (const float*)d_in[3];
    const float* t0p    = (const float*)d_in[4];
    const float* alphap = (const float*)d_in[5];
    const float* delays = (const float*)d_in[6];
    const float* dap    = (const float*)d_in[7];
    const float* gap    = (const float*)d_in[8];

    char* ws = (char*)d_ws;
    float2*         G       = (float2*)(ws);                    // 256,000 B
    unsigned short* audio_h = (unsigned short*)(ws + 294912);   // 524,800 B
    unsigned short* pconv   = (unsigned short*)(ws + 819712);   // 4,096,000 B

    stageAT_kernel<<<190, 512, 0, stream>>>(ing, outg, t0p, alphap,
                                            delays, dap, gap, G,
                                            audio, audio_h);
    conv_mfma_kernel<<<dim3(8, 2, KSPLIT), 512, 0, stream>>>(audio_h, G, early, pconv);
    finish_kernel<<<500, 256, 0, stream>>>(pconv, (float*)d_out);
}

// Round 4
// 41.633 us; speedup vs baseline: 3.0708x; 2.2415x over previous
//
#include <hip/hip_runtime.h>

#define N_FFT 32000
#define NBINS 16001
#define NDL 8
#define NAP 4
#define EARLY_LEN 200
#define T_LEN 32000
#define NB 4

#define ASTRIDE 65600      // padded audio_h stride per batch (halves)
#define APAD 16000         // left zero pad in audio_h

// conv geometry (32x32x16 MFMA implicit GEMM, taps truncated at 16384)
#define KSPLIT 32
#define KRANGE 512         // taps per kz
#define KTOT   16384
#define OB 4096            // outputs per block per batch
#define WSPAN 4576         // OB + KRANGE - 32 logical x window halves per batch
#define XPHYS 5184         // physical (padded) x window halves (max used 5143)
#define HS_ROW_L 536       // hs LDS row halves: KRANGE+24; (536/2)%32==12 (conflict-free quads)
#define HWLEN 544          // KRANGE + 32

struct c32 { float re, im; };

__device__ __forceinline__ c32 cmul(c32 a, c32 b) {
    return { a.re*b.re - a.im*b.im, a.re*b.im + a.im*b.re };
}
__device__ __forceinline__ c32 cdiv(c32 a, c32 b) {
    float inv = 1.0f / (b.re*b.re + b.im*b.im);
    return { (a.re*b.re + a.im*b.im)*inv, (a.im*b.re - a.re*b.im)*inv };
}

typedef _Float16 f16x8 __attribute__((ext_vector_type(8)));
typedef float    f32x16 __attribute__((ext_vector_type(16)));

__device__ __forceinline__ float h2f(unsigned short u) {
    return (float)__builtin_bit_cast(_Float16, u);
}
__device__ __forceinline__ unsigned short f2h(float f) {
    return __builtin_bit_cast(unsigned short, (_Float16)f);
}

// ------- Kernel 1: blocks <125: transfer bins + k2-DFT -> G ----------------
//         blocks >=125: audio f32 -> padded f16 audio_h
__global__ __launch_bounds__(512) void stageAT_kernel(
    const float* __restrict__ ing, const float* __restrict__ outg,
    const float* __restrict__ t0p, const float* __restrict__ alphap,
    const float* __restrict__ delays, const float* __restrict__ dap,
    const float* __restrict__ gap, float2* __restrict__ G,
    const float* __restrict__ audio, unsigned short* __restrict__ audio_h)
{
    __shared__ float2 sxA[129];
    __shared__ float2 tab[256];
    __shared__ float2 pa[512];
    int tid = threadIdx.x;
    int k1 = blockIdx.x;

    if (k1 >= 125) {            // -------- audio conversion part --------
        int i4 = (k1 - 125) * 512 + tid;
        if (i4 >= NB * (ASTRIDE/8)) return;
        int b = i4 / (ASTRIDE/8);
        int q = i4 - b * (ASTRIDE/8);
        int u0 = q * 8 - APAD;
        unsigned r[4];
        if (u0 >= 0 && u0 + 8 <= T_LEN) {
            const float4* ap = (const float4*)(audio + b*T_LEN + u0);
            float4 v0 = ap[0], v1 = ap[1];
            r[0] = f2h(v0.x) | ((unsigned)f2h(v0.y) << 16);
            r[1] = f2h(v0.z) | ((unsigned)f2h(v0.w) << 16);
            r[2] = f2h(v1.x) | ((unsigned)f2h(v1.y) << 16);
            r[3] = f2h(v1.z) | ((unsigned)f2h(v1.w) << 16);
        } else {
            unsigned short hh[8];
            #pragma unroll
            for (int e = 0; e < 8; e++) {
                int u = u0 + e;
                float v = (u >= 0 && u < T_LEN) ? audio[b*T_LEN + u] : 0.0f;
                hh[e] = f2h(v);
            }
            r[0] = hh[0] | ((unsigned)hh[1] << 16);
            r[1] = hh[2] | ((unsigned)hh[3] << 16);
            r[2] = hh[4] | ((unsigned)hh[5] << 16);
            r[3] = hh[6] | ((unsigned)hh[7] << 16);
        }
        ((uint4*)audio_h)[i4] = make_uint4(r[0], r[1], r[2], r[3]);
        return;
    }

    if (tid < 256) {
        float c, s;
        sincosf(2.4544246578366045e-02f * (float)tid, &s, &c);  // 2*pi/256
        tab[tid] = make_float2(c, s);
    }

    const float  TWf = 1.9634954084936207e-04f;   // 2*pi/32000
    const double TWd = 1.9634954084936207740e-04;
    float t0v = t0p[0], alpha = alphap[0];

    for (int base = 0; base < 1032; base += 512) {
        int task = base + tid;
        if (task >= 1032) break;
        int k2 = task >> 3, d = task & 7;
        int f = k1 + 125 * k2;
        if (f > 16000) { if (d == 0) sxA[k2] = make_float2(0.f, 0.f); continue; }

        float wk = TWf * (float)f;
        float cwk, swk;
        sincosf(wk, &swk, &cwk);

        float dval = delays[d];
        float fid = floorf(dval);
        float d_eta = dval - fid;
        float eta = (1.0f - d_eta) / (1.0f + d_eta);
        long long mm = ((long long)f * (long long)fid) % N_FFT;
        float a0 = TWf * (float)mm;
        float c0, s0; sincosf(a0, &s0, &c0);
        c32 z_d = { c0, -s0 };
        c32 num = { eta + cwk, -swk };
        c32 den = { 1.0f + eta*cwk, -eta*swk };
        c32 dvec = cmul(z_d, cdiv(num, den));

        float dsum = dval;
        #pragma unroll
        for (int a = 0; a < NAP; a++) dsum += dap[d*NAP + a];
        float delay_sec = dsum * (1.0f/16000.0f);
        float kf  = expf(-3.0f*delay_sec/t0v * 2.3025850929940457f);
        float kpi = expf(-3.0f*delay_sec/(alpha*t0v) * 2.3025850929940457f);
        float g = 2.0f*kf*kpi/(kf+kpi);
        float p = (kf - kpi)/(kf + kpi);
        c32 fden = { 1.0f + 1e-8f - p*cwk, p*swk };
        c32 filt = cdiv({g, 0.f}, fden);

        c32 ap = {1.f, 0.f};
        #pragma unroll
        for (int a = 0; a < NAP; a++) {
            float dl = dap[d*NAP + a];
            double ph = fmod((double)f * (double)dl, (double)N_FFT);
            float aa = (float)(ph * TWd);
            float ca, sa; sincosf(aa, &sa, &ca);
            float ga = gap[d*NAP + a];
            c32 nume = { 1.0f + ga*ca, ga*sa };
            c32 dene = { ga + ca, sa };
            ap = cmul(ap, cdiv(nume, dene));
        }
        c32 cd = cmul(ap, dvec);
        c32 rc = cmul(filt, cd);
        c32 Dd = { 1.0f + rc.re, rc.im };
        c32 invD = cdiv({1.f, 0.f}, Dd);
        float bg = ing[d];
        c32 t1 = cmul({cd.re*bg, cd.im*bg}, invD);
        c32 t2 = cmul(rc, invD);
        float s1r = t1.re, s1i = t1.im, s2r = t2.re, s2i = t2.im;
        #pragma unroll
        for (int msk = 1; msk < 8; msk <<= 1) {
            s1r += __shfl_xor(s1r, msk);
            s1i += __shfl_xor(s1i, msk);
            s2r += __shfl_xor(s2r, msk);
            s2i += __shfl_xor(s2i, msk);
        }
        c32 denl = { 1.0f - 0.5f*s2r, -0.5f*s2i };
        c32 lam = cdiv({0.5f*s1r, 0.5f*s1i}, denl);
        c32 lr = cmul(lam, filt);
        c32 xv = cmul(invD, {bg + lr.re, lr.im});
        c32 term = cmul(dvec, xv);
        float og = outg[d];
        float trr = term.re * og, tri = term.im * og;
        #pragma unroll
        for (int msk = 1; msk < 8; msk <<= 1) {
            trr += __shfl_xor(trr, msk);
            tri += __shfl_xor(tri, msk);
        }
        if (d == 0) {
            float w = (f == 0 || f == 16000) ? 0.5f : 1.0f;
            sxA[k2] = make_float2(trr * w, tri * w);
        }
    }
    __syncthreads();

    // ---- phase A: split-k2 DFT (2 threads per r) ----
    {
        int r = tid & 255, half = tid >> 8;
        int k2s = half ? 65 : 0, k2e = half ? 129 : 65;
        float ar = 0.f, ai = 0.f;
        int p = (k2s * r) & 255;
        for (int k2 = k2s; k2 < k2e; k2++) {
            float2 X = sxA[k2];
            float2 E = tab[p];
            ar = fmaf(X.x, E.x, fmaf(-X.y, E.y, ar));
            ai = fmaf(X.x, E.y, fmaf( X.y, E.x, ai));
            p = (p + r) & 255;
        }
        pa[tid] = make_float2(ar, ai);
    }
    __syncthreads();
    if (tid < 256) {
        float2 a = pa[tid], b = pa[tid + 256];
        G[k1 * 256 + tid] = make_float2(a.x + b.x, a.y + b.y);
    }
}

// ------- Kernel 2: outer DFT -> h_g[0..16384) f16 (+early), 8-lane split-k1
__global__ __launch_bounds__(512) void stageB_kernel(
    const float2* __restrict__ G, const float* __restrict__ early,
    unsigned short* __restrict__ h_g)
{
    const float TWf = 1.9634954084936207e-04f;   // 2*pi/32000
    int n   = blockIdx.x * 64 + (threadIdx.x >> 3);   // 256*64 = 16384
    int sub = threadIdx.x & 7;
    int k10 = sub * 16;
    int nk1 = (sub == 7) ? 13 : 16;

    int m0 = (n * k10) % N_FFT;                 // exact integer phase
    float er, ei; sincosf(TWf * (float)m0, &ei, &er);
    float wc, wss; sincosf(TWf * (float)n, &wss, &wc);

    float ar = 0.f;
    const float2* gp = G + (n & 255) + k10 * 256;
    #pragma unroll 4
    for (int k = 0; k < nk1; k++) {
        float2 g = gp[k * 256];
        ar = fmaf(g.x, er, fmaf(-g.y, ei, ar));
        float nr = fmaf(er, wc, -(ei*wss));
        float ni = fmaf(er, wss,  (ei*wc));
        er = nr; ei = ni;
    }
    ar += __shfl_xor(ar, 1);
    ar += __shfl_xor(ar, 2);
    ar += __shfl_xor(ar, 4);
    if (sub == 0) {
        float v = ar * (2.0f / (float)N_FFT);
        if (n < EARLY_LEN) v += early[n];
        h_g[n] = f2h(v);
    }
}

// ------- Kernel 3: MFMA conv (KRANGE=512, 56KB LDS, 2 blocks/CU) ----------
__global__ __launch_bounds__(512) void conv_mfma_kernel(
    const unsigned short* __restrict__ audio_h,
    const unsigned short* __restrict__ h_g,
    unsigned short* __restrict__ pconv)
{
    __shared__ __attribute__((aligned(16))) char Sraw[2*XPHYS*2 + 32*HS_ROW_L*2 + HWLEN*2];
    _Float16* xs = (_Float16*)Sraw;                        // [2][XPHYS]
    _Float16* hs = (_Float16*)(Sraw + 2*XPHYS*2);          // [32][HS_ROW_L]
    _Float16* hw = (_Float16*)(Sraw + 2*XPHYS*2 + 32*HS_ROW_L*2); // [HWLEN]
    float*    red = (float*)Sraw;                          // epilogue reuse (32KB)

    int tid = threadIdx.x;
    int lane = tid & 63;
    int w = tid >> 6;
    int bb = w & 1;
    int tq = (w >> 1) & 1;
    int kw = w >> 2;
    int bx = blockIdx.x, bp = blockIdx.y, kz = blockIdx.z;
    int t0 = bx * OB;
    int b0g = bp * 2;
    int K0 = kz * KRANGE;
    int wbase = t0 + K0;

    // ---- stage x windows (2 batches) from pre-converted audio_h ----
    const uint4* xg = (const uint4*)audio_h;
    for (int q = tid; q < 2 * (WSPAN/8); q += 512) {
        int bbs = (q >= WSPAN/8) ? 1 : 0;
        int qq = q - (WSPAN/8) * bbs;
        uint4 v = xg[(size_t)(b0g + bbs) * (ASTRIDE/8) + (wbase >> 3) + qq];
        ((uint4*)xs)[bbs * (XPHYS/8) + qq + (qq >> 3)] = v;
    }
    // ---- stage h window [K0-32, K0+KRANGE) from h_g ----
    {
        unsigned* hw32 = (unsigned*)hw;
        const unsigned* hg32 = (const unsigned*)h_g;
        int sbase = (K0 - 32) >> 1;                 // exact (even)
        for (int j2 = tid; j2 < HWLEN/2; j2 += 512)
            hw32[j2] = (sbase + j2 >= 0) ? hg32[sbase + j2] : 0u;
    }
    __syncthreads();

    // ---- build 32-row shifted band: hs[i][m] = hw[m - i + 31] ----
    // i per lane (tid&31), wave-uniform octet (validated gather)
    {
        const unsigned short* hwu = (const unsigned short*)hw;
        int i  = tid & 31;          // row (shift), constant per thread
        int q0 = tid >> 5;          // 0..15
        #pragma unroll
        for (int e = 0; e < 4; e++) {
            int q = q0 + 16 * e;    // 0..63
            int src = 8 * q - i + 31;              // 0..535 < HWLEN
            unsigned o[4];
            #pragma unroll
            for (int j = 0; j < 4; j++)
                o[j] = (unsigned)hwu[src + 2*j] | ((unsigned)hwu[src + 2*j + 1] << 16);
            *(uint4*)(hs + i * HS_ROW_L + 8 * q) = make_uint4(o[0], o[1], o[2], o[3]);
        }
    }
    __syncthreads();

    int l31 = lane & 31, g = lane >> 5;
    int aBase = l31 * HS_ROW_L + 8 * g;
    int pB0 = 1024 * (2*tq + 0) + 32 * l31 + 8 * g;
    int pB1 = 1024 * (2*tq + 1) + 32 * l31 + 8 * g;
    const _Float16* xb = xs + (bb ? XPHYS : 0);

    f32x16 acc0 = {0,0,0,0,0,0,0,0,0,0,0,0,0,0,0,0};
    f32x16 acc1 = {0,0,0,0,0,0,0,0,0,0,0,0,0,0,0,0};
    #pragma unroll 4
    for (int ksl = 0; ksl < 16; ksl++) {
        int ksg = kw * 16 + ksl;                   // 0..31 (KRANGE/16)
        f16x8 af = *(const f16x8*)(hs + aBase + 16 * ksg);
        int p0 = pB0 + 16 * ksg;
        int p1 = pB1 + 16 * ksg;
        f16x8 bf0 = *(const f16x8*)(xb + p0 + 8 * (p0 >> 6));
        f16x8 bf1 = *(const f16x8*)(xb + p1 + 8 * (p1 >> 6));
        acc0 = __builtin_amdgcn_mfma_f32_32x32x16_f16(af, bf0, acc0, 0, 0, 0);
        acc1 = __builtin_amdgcn_mfma_f32_32x32x16_f16(af, bf1, acc1, 0, 0, 0);
    }
    __syncthreads();
    int slot0 = ((bb * 2 + tq) * 2 + 0) * 1024;
    int slot1 = ((bb * 2 + tq) * 2 + 1) * 1024;
    if (kw == 1) {
        #pragma unroll
        for (int r = 0; r < 16; r++) {
            red[slot0 + r * 64 + lane] = acc0[r];
            red[slot1 + r * 64 + lane] = acc1[r];
        }
    }
    __syncthreads();
    if (kw == 0) {
        unsigned short* po = pconv + (size_t)(kz * NB + b0g + bb) * T_LEN;
        #pragma unroll
        for (int s = 0; s < 2; s++) {
            int T = 2 * tq + s;
            int slot = s ? slot1 : slot0;
            #pragma unroll
            for (int r = 0; r < 16; r += 2) {
                float v0 = (s ? acc1[r]   : acc0[r])   + red[slot + r * 64 + lane];
                float v1 = (s ? acc1[r+1] : acc0[r+1]) + red[slot + (r+1) * 64 + lane];
                int i = (r & 3) + 8 * (r >> 2) + 4 * g;
                int t = t0 + 1024 * T + i + 32 * l31;
                if (t < T_LEN) {
                    unsigned u = f2h(v0) | ((unsigned)f2h(v1) << 16);
                    *(unsigned*)(po + t) = u;
                }
            }
        }
    }
}

// ------- Kernel 4: sum the split-k partials (sole d_out writer) ------------
__global__ void finish_kernel(const unsigned short* __restrict__ pconv,
                              float* __restrict__ out)
{
    int i = blockIdx.x * 256 + threadIdx.x;
    if (i >= NB * T_LEN) return;
    float s = 0.f;
    #pragma unroll
    for (int kz = 0; kz < KSPLIT; kz++)
        s += h2f(pconv[(size_t)kz * NB * T_LEN + i]);
    out[i] = s;
}

extern "C" void kernel_launch(void* const* d_in, const int* in_sizes, int n_in,
                              void* d_out, int out_size, void* d_ws, size_t ws_size,
                              hipStream_t stream) {
    const float* audio  = (const float*)d_in[0];
    const float* early  = (const float*)d_in[1];
    const float* ing    = (const float*)d_in[2];
    const float* outg   = (const float*)d_in[3];
    const float* t0p    = (const float*)d_in[4];
    const float* alphap = (const float*)d_in[5];
    const float* delays = (const float*)d_in[6];
    const float* dap    = (const float*)d_in[7];
    const float* gap    = (const float*)d_in[8];

    char* ws = (char*)d_ws;
    float2*         G       = (float2*)(ws);                    // 256,000 B
    unsigned short* h_g     = (unsigned short*)(ws + 262144);   // 32,768 B
    unsigned short* audio_h = (unsigned short*)(ws + 294912);   // 524,800 B
    unsigned short* pconv   = (unsigned short*)(ws + 819712);   // 8,192,000 B

    stageAT_kernel<<<190, 512, 0, stream>>>(ing, outg, t0p, alphap,
                                            delays, dap, gap, G,
                                            audio, audio_h);
    stageB_kernel<<<256, 512, 0, stream>>>(G, early, h_g);
    conv_mfma_kernel<<<dim3(8, 2, KSPLIT), 512, 0, stream>>>(audio_h, h_g, pconv);
    finish_kernel<<<500, 256, 0, stream>>>(pconv, (float*)d_out);
}